// Round 2
// baseline (142.793 us; speedup 1.0000x reference)
//
#include <hip/hip_runtime.h>
#include <hip/hip_bf16.h>

#define NB 32
#define NN 2048
#define DD 64
#define NCH 32
#define LOG2E 1.44269504088896340736f
#define SQC 0.4246613965f  // sqrt(0.125 * LOG2E)

typedef __attribute__((ext_vector_type(8))) short short8;
typedef __attribute__((ext_vector_type(4))) short short4v;
typedef __attribute__((ext_vector_type(4))) float f32x4;

#define MFMA32K(A, B, C) \
  __builtin_amdgcn_mfma_f32_16x16x32_bf16((A), (B), (C), 0, 0, 0)
#define MFMA16(A, B, C) \
  __builtin_amdgcn_mfma_f32_16x16x16bf16_1k((A), (B), (C), 0, 0, 0)

#define GLOAD_LDS16(gp, lp)                                                   \
  __builtin_amdgcn_global_load_lds(                                          \
      (const __attribute__((address_space(1))) void*)(gp),                   \
      (__attribute__((address_space(3))) void*)(lp), 16, 0, 0)

__device__ __forceinline__ short f2bf(float x) {
  __bf16 h = (__bf16)x;
  return __builtin_bit_cast(short, h);
}

__device__ __forceinline__ float fast_exp2(float x) {
#if __has_builtin(__builtin_amdgcn_exp2f)
  return __builtin_amdgcn_exp2f(x);
#else
  return exp2f(x);
#endif
}

// round-to-nearest bf16 pack of two positive floats: lo -> low short
__device__ __forceinline__ unsigned pack_bf16_rnd(float lo, float hi) {
  unsigned ulo = __builtin_bit_cast(unsigned, lo) + 0x8000u;
  unsigned uhi = __builtin_bit_cast(unsigned, hi) + 0x8000u;
  return __builtin_amdgcn_perm(uhi, ulo, 0x07060302u);
}

// ---------- fused prep: fragment-major bf16 image (K units pre-scaled by
// SQC, V units transposed) + adj int32 -> bitmask.
__global__ __launch_bounds__(256) void prep_fused(
    const float* __restrict__ x, const int* __restrict__ adj,
    short* __restrict__ img, unsigned long long* __restrict__ bits) {
  __shared__ float t[64 * 68];
  const int tid = threadIdx.x;
  const int c = blockIdx.x;
  const int b = blockIdx.y;
  const int r = tid >> 2;
  const int cg = tid & 3;

  const float* src = x + ((size_t)b * NN + c * 64 + r) * DD + cg * 16;
#pragma unroll
  for (int h = 0; h < 4; ++h)
    *(float4*)&t[r * 68 + cg * 16 + h * 4] = ((const float4*)src)[h];
  __syncthreads();

  short* imgc = img + (size_t)(b * NCH + c) * 16 * 512;

  // K units (scaled by SQC)
#pragma unroll
  for (int i = 0; i < 2; ++i) {
    const int kc = tid + i * 256;
    const int u = kc >> 6, l = kc & 63;
    const int nt = u >> 1, ks = u & 1;
    const float* tr = &t[(nt * 16 + (l & 15)) * 68 + ks * 32 + (l >> 4) * 8];
    short8 v;
#pragma unroll
    for (int j = 0; j < 8; ++j) v[j] = f2bf(tr[j] * SQC);
    *(short8*)&imgc[(size_t)u * 512 + l * 8] = v;
  }
  // V units (unscaled, transposed gather)
#pragma unroll
  for (int i = 0; i < 2; ++i) {
    const int vc = tid + i * 256;
    const int u = vc >> 6, l = vc & 63;
    const int dt = u >> 1, ntp = u & 1;
    const int d = dt * 16 + (l & 15);
    const int k0 = ntp * 32 + ((l >> 4) << 2);
    short8 o;
#pragma unroll
    for (int h = 0; h < 2; ++h)
#pragma unroll
      for (int r2 = 0; r2 < 4; ++r2)
        o[h * 4 + r2] = f2bf(t[(k0 + h * 16 + r2) * 68 + d]);
    *(short8*)&imgc[(size_t)(8 + u) * 512 + l * 8] = o;
  }

  // adj -> bitmask: 16 entries/thread
  const int base = (b * NCH + c) * 4096;
#pragma unroll
  for (int k = 0; k < 16; ++k) {
    const int idx = base + k * 256 + tid;
    unsigned long long m = __ballot(adj[idx] > 0);
    if ((tid & 63) == 0) bits[idx >> 6] = m;
  }
}

// one chunk's compute: 2 Q-tiles (32 rows) per wave, 64 keys.
// LDS K/V fragments are read once and amortized over both Q-tiles.
__device__ __forceinline__ void chunk_body(
    const short* __restrict__ sB, unsigned long long a0, unsigned long long a1,
    int quad, int l, const short8 (&qf)[2][2], const short4v& ones,
    f32x4 (&acc)[2][4], f32x4 (&acl)[2]) {
  a0 >>= (quad * 4);
  a1 >>= (quad * 4);
  const unsigned lo0 = (unsigned)a0, hi0 = (unsigned)(a0 >> 32);
  const unsigned lo1 = (unsigned)a1, hi1 = (unsigned)(a1 >> 32);
  const short* sK = sB;
  const short* sV = sB + 4096;

#pragma unroll
  for (int ntp = 0; ntp < 2; ++ntp) {
    short4v pf[2][2];  // [h][qt]
#pragma unroll
    for (int h = 0; h < 2; ++h) {
      const int nt = ntp * 2 + h;
      f32x4 s0 = {0.f, 0.f, 0.f, 0.f};
      f32x4 s1 = {0.f, 0.f, 0.f, 0.f};
#pragma unroll
      for (int ks = 0; ks < 2; ++ks) {
        short8 kf = *(const short8*)&sK[(nt * 2 + ks) * 512 + l * 8];
        s0 = MFMA32K(kf, qf[0][ks], s0);
        s1 = MFMA32K(kf, qf[1][ks], s1);
      }
      const unsigned w0 = (nt < 2) ? lo0 : hi0;
      const unsigned w1 = (nt < 2) ? lo1 : hi1;
      const int sh = (nt & 1) * 16;
      float p0[4], p1[4];
#pragma unroll
      for (int r = 0; r < 4; ++r) {
        float e0 = fast_exp2(s0[r]);
        float e1 = fast_exp2(s1[r]);
        p0[r] = ((w0 >> (sh + r)) & 1u) ? e0 : 0.f;
        p1[r] = ((w1 >> (sh + r)) & 1u) ? e1 : 0.f;
      }
      uint2 u0, u1;
      u0.x = pack_bf16_rnd(p0[0], p0[1]);
      u0.y = pack_bf16_rnd(p0[2], p0[3]);
      u1.x = pack_bf16_rnd(p1[0], p1[1]);
      u1.y = pack_bf16_rnd(p1[2], p1[3]);
      pf[h][0] = __builtin_bit_cast(short4v, u0);
      pf[h][1] = __builtin_bit_cast(short4v, u1);
      acl[0] = MFMA16(ones, pf[h][0], acl[0]);
      acl[1] = MFMA16(ones, pf[h][1], acl[1]);
    }
#pragma unroll
    for (int dt = 0; dt < 4; ++dt) {
      short8 vv = *(const short8*)&sV[(dt * 2 + ntp) * 512 + l * 8];
      short4v vlo, vhi;
      vlo[0] = vv[0]; vlo[1] = vv[1]; vlo[2] = vv[2]; vlo[3] = vv[3];
      vhi[0] = vv[4]; vhi[1] = vv[5]; vhi[2] = vv[6]; vhi[3] = vv[7];
      acc[0][dt] = MFMA16(vlo, pf[0][0], acc[0][dt]);
      acc[1][dt] = MFMA16(vlo, pf[0][1], acc[1][dt]);
      acc[0][dt] = MFMA16(vhi, pf[1][0], acc[0][dt]);
      acc[1][dt] = MFMA16(vhi, pf[1][1], acc[1][dt]);
    }
  }
}

// ---------- main: 128-thread blocks (2 waves x 2 Q-tiles = 64 rows), grid
// 1024, 32 KB LDS -> 4 independent blocks/CU. Halves LDS reads per FLOP vs
// the 1-Q-tile version while keeping 4-way cross-block barrier overlap.
// beta&7 = XCD so each XCD keeps 4 batches' img (~2.1 MB) L2-resident.
__global__ __launch_bounds__(128, 2) void gat_flash10(
    const short* __restrict__ img, const unsigned long long* __restrict__ adjb,
    float* __restrict__ out) {
  __shared__ short sI[2][8192];  // double-buffered 16 KB chunk

  const int beta = blockIdx.x;
  const int xcd = beta & 7;
  const int idx = beta >> 3;        // 0..127
  const int xq = idx & 31;          // 64-row q-group
  const int b = xcd * 4 + (idx >> 5);

  const int tid = threadIdx.x;
  const int w = tid >> 6;           // 0..1
  const int l = tid & 63;
  const int lane16 = l & 15;
  const int quad = l >> 4;
  const int qbase = xq * 64 + w * 32;

  const short* img_b = img + (size_t)b * NCH * 16 * 512;

  // Q B-frags from the pre-scaled img K-units of q-chunk xq;
  // wave w owns 16-row tiles nt = w*2+qt of that chunk.
  short8 qf[2][2];
#pragma unroll
  for (int qt = 0; qt < 2; ++qt)
#pragma unroll
    for (int ks = 0; ks < 2; ++ks)
      qf[qt][ks] = *(const short8*)&img_b[((size_t)xq * 16 +
                                          (w * 2 + qt) * 2 + ks) * 512 + l * 8];

  f32x4 acc[2][4], acl[2];
#pragma unroll
  for (int qt = 0; qt < 2; ++qt) {
    acl[qt] = {0.f, 0.f, 0.f, 0.f};
#pragma unroll
    for (int dt = 0; dt < 4; ++dt) acc[qt][dt] = {0.f, 0.f, 0.f, 0.f};
  }
  short4v ones;
  ones[0] = 0x3F80; ones[1] = 0x3F80; ones[2] = 0x3F80; ones[3] = 0x3F80;

  const unsigned long long* ar0 = adjb + (size_t)(qbase + lane16) * NCH;
  const unsigned long long* ar1 = adjb + (size_t)(qbase + 16 + lane16) * NCH;

  // prologue: stage chunk 0 (16 KB = 16 units, 8 per wave)
#pragma unroll
  for (int i = 0; i < 8; ++i) {
    const int u = i * 2 + w;
    GLOAD_LDS16(img_b + (size_t)u * 512 + l * 8, &sI[0][u * 512]);
  }
  __syncthreads();

#pragma unroll 2
  for (int c = 0; c < 32; ++c) {
    const int cur = c & 1;
    if (c < 31) {
      const short* p = img_b + (size_t)(c + 1) * 8192;
#pragma unroll
      for (int i = 0; i < 8; ++i) {
        const int u = i * 2 + w;
        GLOAD_LDS16(p + (size_t)u * 512 + l * 8, &sI[cur ^ 1][u * 512]);
      }
    }
    chunk_body(sI[cur], ar0[c], ar1[c], quad, l, qf, ones, acc, acl);
    __syncthreads();
  }

  // ---- epilogue ----
#pragma unroll
  for (int qt = 0; qt < 2; ++qt) {
    const float inv = 1.0f / acl[qt][0];
    float* op =
        out + ((size_t)b * NN + qbase + qt * 16 + lane16) * DD + quad * 4;
#pragma unroll
    for (int dt = 0; dt < 4; ++dt) {
      float4 o;
      o.x = acc[qt][dt][0] * inv;
      o.y = acc[qt][dt][1] * inv;
      o.z = acc[qt][dt][2] * inv;
      o.w = acc[qt][dt][3] * inv;
      *(float4*)(op + dt * 16) = o;
    }
  }
}

extern "C" void kernel_launch(void* const* d_in, const int* in_sizes, int n_in,
                              void* d_out, int out_size, void* d_ws,
                              size_t ws_size, hipStream_t stream) {
  const float* x = (const float*)d_in[0];
  const int* adj = (const int*)d_in[1];
  float* out = (float*)d_out;

  short* img = (short*)d_ws;  // 16 MB fragment-major image
  unsigned long long* adjb =
      (unsigned long long*)(img + (size_t)NB * NCH * 16 * 512);  // 512 KB

  prep_fused<<<dim3(NCH, NB), 256, 0, stream>>>(x, adj, img, adjb);
  gat_flash10<<<1024, 128, 0, stream>>>(img, adjb, out);
}

// Round 3
// 132.118 us; speedup vs baseline: 1.0808x; 1.0808x over previous
//
#include <hip/hip_runtime.h>
#include <hip/hip_bf16.h>

#define NB 32
#define NN 2048
#define DD 64
#define NCH 32
#define SQC 0.4246613965f  // sqrt(0.125 * LOG2E); applied to both Q and K

typedef __attribute__((ext_vector_type(8))) short short8;
typedef __attribute__((ext_vector_type(4))) float f32x4;
typedef __attribute__((ext_vector_type(4))) unsigned uint4v;

#define MFMA32K(A, B, C) \
  __builtin_amdgcn_mfma_f32_16x16x32_bf16((A), (B), (C), 0, 0, 0)

#define GLOAD_LDS16(gp, lp)                                                   \
  __builtin_amdgcn_global_load_lds(                                          \
      (const __attribute__((address_space(1))) void*)(gp),                   \
      (__attribute__((address_space(3))) void*)(lp), 16, 0, 0)

__device__ __forceinline__ short f2bf(float x) {
  __bf16 h = (__bf16)x;
  return __builtin_bit_cast(short, h);
}

__device__ __forceinline__ float fast_exp2(float x) {
#if __has_builtin(__builtin_amdgcn_exp2f)
  return __builtin_amdgcn_exp2f(x);
#else
  return exp2f(x);
#endif
}

// round-to-nearest bf16 pack of two positive floats: lo -> low short
__device__ __forceinline__ unsigned pack_bf16_rnd(float lo, float hi) {
  unsigned ulo = __builtin_bit_cast(unsigned, lo) + 0x8000u;
  unsigned uhi = __builtin_bit_cast(unsigned, hi) + 0x8000u;
  return __builtin_amdgcn_perm(uhi, ulo, 0x07060302u);
}

// Key permutation: within each 32-key group, tile h (h=0,1) row r maps to
// key32 = (r>>2)*8 + h*4 + (r&3). This makes the QK^T output (C-layout:
// quad q holds rows q*4+r) land directly in 16x16x32 B-operand layout
// (quad q holds k = q*8 + 0..7), so PV and the row-sum run at full K=32
// MFMA rate with zero cross-lane shuffles.

// ---------- fused prep, pure streaming (no LDS): fragment-major bf16 image
// (K units pre-scaled by SQC with permuted rows, V units transposed with
// matching k-order) + adj int32 -> bitmask.
__global__ __launch_bounds__(256) void prep_fused(
    const float* __restrict__ x, const int* __restrict__ adj,
    short* __restrict__ img, unsigned long long* __restrict__ bits) {
  const int tid = threadIdx.x;
  const int c = blockIdx.x;
  const int b = blockIdx.y;
  const float* xb = x + ((size_t)b * NN + c * 64) * DD;
  short* imgc = img + (size_t)(b * NCH + c) * 16 * 512;

  // K units (scaled by SQC, permuted rows): units 0..7 (nt*2+ks)
#pragma unroll
  for (int i = 0; i < 2; ++i) {
    const int kc = tid + i * 256;
    const int u = kc >> 6, l = kc & 63;
    const int nt = u >> 1, ks = u & 1;
    const int r16 = l & 15;
    const int row =
        (nt >> 1) * 32 + (r16 >> 2) * 8 + (nt & 1) * 4 + (r16 & 3);
    const float* src = xb + row * DD + ks * 32 + (l >> 4) * 8;
    float4 f0 = ((const float4*)src)[0];
    float4 f1 = ((const float4*)src)[1];
    short8 v;
    v[0] = f2bf(f0.x * SQC); v[1] = f2bf(f0.y * SQC);
    v[2] = f2bf(f0.z * SQC); v[3] = f2bf(f0.w * SQC);
    v[4] = f2bf(f1.x * SQC); v[5] = f2bf(f1.y * SQC);
    v[6] = f2bf(f1.z * SQC); v[7] = f2bf(f1.w * SQC);
    *(short8*)&imgc[(size_t)u * 512 + l * 8] = v;
  }
  // V units (transposed; element j of quad g holds key32 = g*8+j):
  // units 8..15 (8 + dt*2 + ntp)
#pragma unroll
  for (int i = 0; i < 2; ++i) {
    const int vc = tid + i * 256;
    const int u = vc >> 6, l = vc & 63;
    const int dt = u >> 1, ntp = u & 1;
    const int d = dt * 16 + (l & 15);
    const int k0 = ntp * 32 + (l >> 4) * 8;
    short8 o;
#pragma unroll
    for (int j = 0; j < 8; ++j) o[j] = f2bf(xb[(size_t)(k0 + j) * DD + d]);
    *(short8*)&imgc[(size_t)(8 + u) * 512 + l * 8] = o;
  }

  // adj -> bitmask: flat partition, 16 entries/thread, coalesced
  const int base = (b * NCH + c) * 4096;
#pragma unroll
  for (int k = 0; k < 16; ++k) {
    const int idx = base + k * 256 + tid;
    unsigned long long m = __ballot(adj[idx] > 0);
    if ((tid & 63) == 0) bits[idx >> 6] = m;
  }
}

// one chunk's compute: 1 Q-tile per wave, 64 keys, all-K=32 MFMA.
// Per chunk: 8 QK + 2 rowsum + 8 PV = 18 mfma_16x16x32 (vs 8+20 mixed).
__device__ __forceinline__ void chunk_body(
    const short* __restrict__ sB, unsigned long long a, int quad, int l,
    const short8 (&qf)[2], const short8& ones8, f32x4 (&acc)[4], f32x4& acl) {
  const unsigned lo = (unsigned)(a >> (quad * 8));
  const unsigned hi = (unsigned)(a >> (32 + quad * 8));
  const short* sK = sB;
  const short* sV = sB + 4096;

#pragma unroll
  for (int ntp = 0; ntp < 2; ++ntp) {
    const unsigned wm = ntp ? hi : lo;
    f32x4 s0 = {0.f, 0.f, 0.f, 0.f};
    f32x4 s1 = {0.f, 0.f, 0.f, 0.f};
#pragma unroll
    for (int ks = 0; ks < 2; ++ks) {
      short8 kf0 = *(const short8*)&sK[((ntp * 2 + 0) * 2 + ks) * 512 + l * 8];
      short8 kf1 = *(const short8*)&sK[((ntp * 2 + 1) * 2 + ks) * 512 + l * 8];
      s0 = MFMA32K(kf0, qf[ks], s0);
      s1 = MFMA32K(kf1, qf[ks], s1);
    }
    // key32 of s0[r] = quad*8 + r; of s1[r] = quad*8 + 4 + r (by prep perm)
    float p[8];
#pragma unroll
    for (int r = 0; r < 4; ++r) {
      float e0 = fast_exp2(s0[r]);
      float e1 = fast_exp2(s1[r]);
      p[r] = ((wm >> r) & 1u) ? e0 : 0.f;
      p[4 + r] = ((wm >> (4 + r)) & 1u) ? e1 : 0.f;
    }
    uint4v pu;
    pu[0] = pack_bf16_rnd(p[0], p[1]);
    pu[1] = pack_bf16_rnd(p[2], p[3]);
    pu[2] = pack_bf16_rnd(p[4], p[5]);
    pu[3] = pack_bf16_rnd(p[6], p[7]);
    short8 pc = __builtin_bit_cast(short8, pu);
    acl = MFMA32K(ones8, pc, acl);
#pragma unroll
    for (int dt = 0; dt < 4; ++dt) {
      short8 vv = *(const short8*)&sV[(dt * 2 + ntp) * 512 + l * 8];
      acc[dt] = MFMA32K(vv, pc, acc[dt]);
    }
  }
}

// ---------- main: flash9 host structure (best measured): 256-thread blocks,
// 1 Q-tile/wave, grid 1024, 32 KB LDS -> 4 blocks/CU = 16 waves/CU.
// beta&7 = XCD so each XCD keeps 4 batches' img (~2.1 MB) L2-resident.
__global__ __launch_bounds__(256, 4) void gat_flash11(
    const short* __restrict__ img, const unsigned long long* __restrict__ adjb,
    float* __restrict__ out) {
  __shared__ short sI[2][8192];  // double-buffered 16 KB chunk

  const int beta = blockIdx.x;
  const int xcd = beta & 7;
  const int idx = beta >> 3;        // 0..127
  const int xq = idx & 31;          // 64-row q-group
  const int b = xcd * 4 + (idx >> 5);

  const int tid = threadIdx.x;
  const int w = tid >> 6;
  const int l = tid & 63;
  const int lane16 = l & 15;
  const int quad = l >> 4;

  const short* img_b = img + (size_t)b * NCH * 16 * 512;

  // Q B-frags from the pre-scaled img K-units of q-chunk xq; wave w owns
  // tile nt=w. Due to the key permutation, col c of this tile is query
  // qrow = xq*64 + (w>>1)*32 + (c>>2)*8 + (w&1)*4 + (c&3).
  short8 qf[2];
#pragma unroll
  for (int ks = 0; ks < 2; ++ks)
    qf[ks] =
        *(const short8*)&img_b[((size_t)xq * 16 + w * 2 + ks) * 512 + l * 8];

  f32x4 acc[4];
  f32x4 acl = {0.f, 0.f, 0.f, 0.f};
#pragma unroll
  for (int dt = 0; dt < 4; ++dt) acc[dt] = {0.f, 0.f, 0.f, 0.f};

  short8 ones8;
#pragma unroll
  for (int j = 0; j < 8; ++j) ones8[j] = 0x3F80;

  const int qrow =
      xq * 64 + (w >> 1) * 32 + (lane16 >> 2) * 8 + (w & 1) * 4 + (lane16 & 3);
  const unsigned long long* ar = adjb + (size_t)qrow * NCH;

  // prologue: stage chunk 0 (16 units, 4 per wave)
#pragma unroll
  for (int i = 0; i < 4; ++i) {
    const int u = i * 4 + w;
    GLOAD_LDS16(img_b + (size_t)u * 512 + l * 8, &sI[0][u * 512]);
  }
  __syncthreads();

#pragma unroll 2
  for (int c = 0; c < 32; ++c) {
    const int cur = c & 1;
    if (c < 31) {
      const short* p = img_b + (size_t)(c + 1) * 8192;
#pragma unroll
      for (int i = 0; i < 4; ++i) {
        const int u = i * 4 + w;
        GLOAD_LDS16(p + (size_t)u * 512 + l * 8, &sI[cur ^ 1][u * 512]);
      }
    }
    chunk_body(sI[cur], ar[c], quad, l, qf, ones8, acc, acl);
    __syncthreads();
  }

  // ---- epilogue ----
  const float inv = 1.0f / acl[0];
  float* op = out + ((size_t)b * NN + qrow) * DD + quad * 4;
#pragma unroll
  for (int dt = 0; dt < 4; ++dt) {
    float4 o;
    o.x = acc[dt][0] * inv;
    o.y = acc[dt][1] * inv;
    o.z = acc[dt][2] * inv;
    o.w = acc[dt][3] * inv;
    *(float4*)(op + dt * 16) = o;
  }
}

extern "C" void kernel_launch(void* const* d_in, const int* in_sizes, int n_in,
                              void* d_out, int out_size, void* d_ws,
                              size_t ws_size, hipStream_t stream) {
  const float* x = (const float*)d_in[0];
  const int* adj = (const int*)d_in[1];
  float* out = (float*)d_out;

  short* img = (short*)d_ws;  // 16 MB fragment-major image
  unsigned long long* adjb =
      (unsigned long long*)(img + (size_t)NB * NCH * 16 * 512);  // 512 KB

  prep_fused<<<dim3(NCH, NB), 256, 0, stream>>>(x, adj, img, adjb);
  gat_flash11<<<1024, 256, 0, stream>>>(img, adjb, out);
}

// Round 4
// 130.698 us; speedup vs baseline: 1.0925x; 1.0109x over previous
//
#include <hip/hip_runtime.h>
#include <hip/hip_bf16.h>

#define NB 32
#define NN 2048
#define DD 64
#define NCH 32
#define SQC 0.4246613965f  // sqrt(0.125 * LOG2E); applied to both Q and K

typedef __attribute__((ext_vector_type(8))) short short8;
typedef __attribute__((ext_vector_type(4))) float f32x4;
typedef __attribute__((ext_vector_type(4))) unsigned uint4v;
typedef __attribute__((ext_vector_type(4))) int int4v;

#define MFMA32K(A, B, C) \
  __builtin_amdgcn_mfma_f32_16x16x32_bf16((A), (B), (C), 0, 0, 0)

#define GLOAD_LDS16(gp, lp)                                                   \
  __builtin_amdgcn_global_load_lds(                                          \
      (const __attribute__((address_space(1))) void*)(gp),                   \
      (__attribute__((address_space(3))) void*)(lp), 16, 0, 0)

__device__ __forceinline__ short f2bf(float x) {
  __bf16 h = (__bf16)x;
  return __builtin_bit_cast(short, h);
}

__device__ __forceinline__ float fast_exp2(float x) {
#if __has_builtin(__builtin_amdgcn_exp2f)
  return __builtin_amdgcn_exp2f(x);
#else
  return exp2f(x);
#endif
}

// round-to-nearest bf16 pack of two positive floats: lo -> low short
__device__ __forceinline__ unsigned pack_bf16_rnd(float lo, float hi) {
  unsigned ulo = __builtin_bit_cast(unsigned, lo) + 0x8000u;
  unsigned uhi = __builtin_bit_cast(unsigned, hi) + 0x8000u;
  return __builtin_amdgcn_perm(uhi, ulo, 0x07060302u);
}

// Key permutation (unchanged from flash11): within each 32-key group, tile h
// row r maps to key32 = (r>>2)*8 + h*4 + (r&3), so the QK^T C-layout lands
// directly in 16x16x32 B-operand layout and PV/rowsum run at full K=32 rate.

// ---------- fused prep, pure streaming: fragment-major bf16 image + adj ->
// per-(row,quad) packed mask BYTES (bit j of byte (qrow,quad,s) =
// adj[qrow][s*32 + quad*8 + j]), stored as uints mbw[qrow*64 + quad*16 + s/4]
// so the main kernel loads ONE uint per 4 sub-chunks.
__global__ __launch_bounds__(256) void prep_fused(
    const float* __restrict__ x, const int* __restrict__ adj,
    short* __restrict__ img, unsigned* __restrict__ mbw) {
  const int tid = threadIdx.x;
  const int c = blockIdx.x;
  const int b = blockIdx.y;
  const float* xb = x + ((size_t)b * NN + c * 64) * DD;
  short* imgc = img + (size_t)(b * NCH + c) * 16 * 512;

  // K units (scaled by SQC, permuted rows): units 0..7 (nt*2+ks)
#pragma unroll
  for (int i = 0; i < 2; ++i) {
    const int kc = tid + i * 256;
    const int u = kc >> 6, l = kc & 63;
    const int nt = u >> 1, ks = u & 1;
    const int r16 = l & 15;
    const int row =
        (nt >> 1) * 32 + (r16 >> 2) * 8 + (nt & 1) * 4 + (r16 & 3);
    const float* src = xb + row * DD + ks * 32 + (l >> 4) * 8;
    float4 f0 = ((const float4*)src)[0];
    float4 f1 = ((const float4*)src)[1];
    short8 v;
    v[0] = f2bf(f0.x * SQC); v[1] = f2bf(f0.y * SQC);
    v[2] = f2bf(f0.z * SQC); v[3] = f2bf(f0.w * SQC);
    v[4] = f2bf(f1.x * SQC); v[5] = f2bf(f1.y * SQC);
    v[6] = f2bf(f1.z * SQC); v[7] = f2bf(f1.w * SQC);
    *(short8*)&imgc[(size_t)u * 512 + l * 8] = v;
  }
  // V units (transposed; element j of quad g holds key32 = g*8+j):
  // units 8..15 (8 + dt*2 + ntp)
#pragma unroll
  for (int i = 0; i < 2; ++i) {
    const int vc = tid + i * 256;
    const int u = vc >> 6, l = vc & 63;
    const int dt = u >> 1, ntp = u & 1;
    const int d = dt * 16 + (l & 15);
    const int k0 = ntp * 32 + (l >> 4) * 8;
    short8 o;
#pragma unroll
    for (int j = 0; j < 8; ++j) o[j] = f2bf(xb[(size_t)(k0 + j) * DD + d]);
    *(short8*)&imgc[(size_t)(8 + u) * 512 + l * 8] = o;
  }

  // adj -> packed mask bytes. Block (c,b) owns rows R0, R0+1.
  const int R0 = (b * NCH + c) * 2;
  if (tid < 128) {
    const int qrow = R0 + (tid >> 6);
    const int u = tid & 63;  // uint index within row (quad = u>>4)
    const int* ap =
        adj + (size_t)qrow * 2048 + (u & 15) * 128 + (u >> 4) * 8;
    unsigned mw = 0;
#pragma unroll
    for (int j = 0; j < 4; ++j) {
      int4v a0 = *(const int4v*)(ap + j * 32);
      int4v a1 = *(const int4v*)(ap + j * 32 + 4);
      unsigned by = 0;
#pragma unroll
      for (int bit = 0; bit < 4; ++bit) {
        by |= (a0[bit] > 0 ? 1u : 0u) << bit;
        by |= (a1[bit] > 0 ? 1u : 0u) << (4 + bit);
      }
      mw |= by << (8 * j);
    }
    mbw[(size_t)qrow * 64 + u] = mw;
  }
}

// One pipeline phase: [counted-vmcnt wait][raw barrier][issue stage s+3]
// [setprio(1) compute sub-chunk s][setprio(0)]. Phase index P == s&3 ==
// ring index; (P+3)&3 = stage target ring; np = parity of the sub-chunk.
#define PHASE_BODY(P, VMCNT_STR, DO_STAGE, C2EXPR)                          \
  {                                                                         \
    asm volatile("s_waitcnt vmcnt(" VMCNT_STR ")" ::: "memory");            \
    __builtin_amdgcn_s_barrier();                                           \
    if (DO_STAGE) {                                                         \
      const int C2 = (C2EXPR);                                              \
      const short* gs = img_b + (size_t)C2 * 8192 + l * 8;                  \
      GLOAD_LDS16(gs + ((((P) + 3) & 1) * 4 + w) * 512,                     \
                  &sI[((P) + 3) & 3][w * 512 + l * 8]);                     \
      GLOAD_LDS16(gs + (8 + 2 * w + (((P) + 3) & 1)) * 512,                 \
                  &sI[((P) + 3) & 3][(4 + w) * 512 + l * 8]);               \
    }                                                                       \
    __builtin_amdgcn_s_setprio(1);                                          \
    const short* ring = sI[(P) & 3];                                        \
    const unsigned wm8 = (mw >> (8 * (P))) & 0xffu;                         \
    f32x4 s0 = {0.f, 0.f, 0.f, 0.f}, s1 = {0.f, 0.f, 0.f, 0.f};            \
    s0 = MFMA32K(*(const short8*)&ring[0 * 512 + l * 8], qf[0], s0);        \
    s0 = MFMA32K(*(const short8*)&ring[1 * 512 + l * 8], qf[1], s0);        \
    s1 = MFMA32K(*(const short8*)&ring[2 * 512 + l * 8], qf[0], s1);        \
    s1 = MFMA32K(*(const short8*)&ring[3 * 512 + l * 8], qf[1], s1);        \
    float e0[4], e1[4];                                                     \
    _Pragma("unroll") for (int r = 0; r < 4; ++r) {                         \
      float a0 = fast_exp2(s0[r]);                                          \
      float a1 = fast_exp2(s1[r]);                                          \
      e0[r] = ((wm8 >> r) & 1u) ? a0 : 0.f;                                 \
      e1[r] = ((wm8 >> (4 + r)) & 1u) ? a1 : 0.f;                           \
    }                                                                       \
    uint4v pu;                                                              \
    pu[0] = pack_bf16_rnd(e0[0], e0[1]);                                    \
    pu[1] = pack_bf16_rnd(e0[2], e0[3]);                                    \
    pu[2] = pack_bf16_rnd(e1[0], e1[1]);                                    \
    pu[3] = pack_bf16_rnd(e1[2], e1[3]);                                    \
    short8 pc = __builtin_bit_cast(short8, pu);                             \
    acl = MFMA32K(ones8, pc, acl);                                          \
    _Pragma("unroll") for (int dt = 0; dt < 4; ++dt)                        \
        acc[dt] = MFMA32K(*(const short8*)&ring[(4 + dt) * 512 + l * 8],    \
                          pc, acc[dt]);                                     \
    __builtin_amdgcn_s_setprio(0);                                          \
  }

// ---------- main: flash11 structure (256-thr, 1 Q-tile/wave, grid 1024,
// 32 KB LDS, 4 blocks/CU) but with a 4-ring of 8 KB sub-chunks (32 keys),
// depth-3 prefetch, raw s_barrier + counted vmcnt(4) — no vmcnt(0) drain
// anywhere in the main loop (T3+T4), plus setprio around compute (T5).
__global__ __launch_bounds__(256, 4) void gat_flash12(
    const short* __restrict__ img, const unsigned* __restrict__ mbw,
    float* __restrict__ out) {
  __shared__ short sI[4][4096];  // 4-ring of 8 KB sub-chunk buffers

  const int beta = blockIdx.x;
  const int xcd = beta & 7;
  const int idx = beta >> 3;        // 0..127
  const int xq = idx & 31;          // 64-row q-group
  const int b = xcd * 4 + (idx >> 5);

  const int tid = threadIdx.x;
  const int w = tid >> 6;
  const int l = tid & 63;
  const int lane16 = l & 15;
  const int quad = l >> 4;

  const short* img_b = img + (size_t)b * NCH * 16 * 512;

  // Q B-frags from the pre-scaled img K-units of q-chunk xq (wave w = tile w)
  short8 qf[2];
#pragma unroll
  for (int ks = 0; ks < 2; ++ks)
    qf[ks] =
        *(const short8*)&img_b[((size_t)xq * 16 + w * 2 + ks) * 512 + l * 8];

  f32x4 acc[4];
  f32x4 acl = {0.f, 0.f, 0.f, 0.f};
#pragma unroll
  for (int dt = 0; dt < 4; ++dt) acc[dt] = {0.f, 0.f, 0.f, 0.f};

  short8 ones8;
#pragma unroll
  for (int j = 0; j < 8; ++j) ones8[j] = 0x3F80;

  // permuted query row (same perm as keys; see flash11)
  const int qrow =
      xq * 64 + (w >> 1) * 32 + (lane16 >> 2) * 8 + (w & 1) * 4 + (lane16 & 3);
  const unsigned* arm = mbw + (size_t)qrow * 64 + quad * 16;

  unsigned mw_nxt = arm[0];

  // prologue: stage sub-chunks 0,1,2 into rings 0,1,2 (C = s>>1, np = s&1)
  {
    const short* g0 = img_b + l * 8;  // C=0
    GLOAD_LDS16(g0 + (0 * 4 + w) * 512, &sI[0][w * 512 + l * 8]);
    GLOAD_LDS16(g0 + (8 + 2 * w + 0) * 512, &sI[0][(4 + w) * 512 + l * 8]);
    GLOAD_LDS16(g0 + (1 * 4 + w) * 512, &sI[1][w * 512 + l * 8]);
    GLOAD_LDS16(g0 + (8 + 2 * w + 1) * 512, &sI[1][(4 + w) * 512 + l * 8]);
    const short* g1 = img_b + 8192 + l * 8;  // C=1
    GLOAD_LDS16(g1 + (0 * 4 + w) * 512, &sI[2][w * 512 + l * 8]);
    GLOAD_LDS16(g1 + (8 + 2 * w + 0) * 512, &sI[2][(4 + w) * 512 + l * 8]);
  }

  // main: 15 macro-iters x 4 phases (sub-chunks 0..59), then peeled tail
  for (int M = 0; M < 15; ++M) {
    const unsigned mw = mw_nxt;
    mw_nxt = arm[M + 1];
    PHASE_BODY(0, "4", true, 2 * M + 1);
    PHASE_BODY(1, "4", true, 2 * M + 2);
    PHASE_BODY(2, "4", true, 2 * M + 2);
    PHASE_BODY(3, "4", true, 2 * M + 3);
  }
  {
    const unsigned mw = mw_nxt;  // arm[15]
    PHASE_BODY(0, "4", true, 31);   // stages sub-chunk 63
    PHASE_BODY(1, "4", false, 0);
    PHASE_BODY(2, "2", false, 0);
    PHASE_BODY(3, "0", false, 0);
  }

  // ---- epilogue ----
  const float inv = 1.0f / acl[0];
  float* op = out + ((size_t)b * NN + qrow) * DD + quad * 4;
#pragma unroll
  for (int dt = 0; dt < 4; ++dt) {
    float4 o;
    o.x = acc[dt][0] * inv;
    o.y = acc[dt][1] * inv;
    o.z = acc[dt][2] * inv;
    o.w = acc[dt][3] * inv;
    *(float4*)(op + dt * 16) = o;
  }
}

extern "C" void kernel_launch(void* const* d_in, const int* in_sizes, int n_in,
                              void* d_out, int out_size, void* d_ws,
                              size_t ws_size, hipStream_t stream) {
  const float* x = (const float*)d_in[0];
  const int* adj = (const int*)d_in[1];
  float* out = (float*)d_out;

  short* img = (short*)d_ws;  // 16 MB fragment-major image
  unsigned* mbw = (unsigned*)(img + (size_t)NB * NCH * 16 * 512);  // 512 KB

  prep_fused<<<dim3(NCH, NB), 256, 0, stream>>>(x, adj, img, mbw);
  gat_flash12<<<1024, 256, 0, stream>>>(img, mbw, out);
}